// Round 10
// baseline (181.394 us; speedup 1.0000x reference)
//
#include <hip/hip_runtime.h>
#include <math.h>

#define NPTS 40
#define NN   1600
#define WID  128

// stats layout (float offsets in stA/stB): D/R/C indexed [i*40+a]
#define ST_D  0
#define ST_R  5120
#define ST_C  10240
#define ST_TR 15360
#define ST_T  15488
// zero range for stB: [ST_R, ST_T+128) = [5120, 15616)

// coefficient matrices per hidden layer: 15 mats of [i*128+o]
#define CM_SZ1 16384

// accumulator layout (within ACC buffer)
#define PVA 0
#define PVB 40
#define PDG 80
#define A_SOFF 120
#define A_SDG  121
#define A_ISC  122

// workspace layout (float offsets)
#define WS_XTA   0
#define WS_XTB   204800
#define WS_STA   409600
#define WS_STB   425984
#define WS_CM0   442368
#define WS_CM1   688128
#define WS_PRAW  933888
#define WS_ACC   935488
#define WS_TOTAL 935616

static __device__ __forceinline__ float lrelu(float v) {
    return v >= 0.f ? v : 0.01f * v;
}

static __device__ __forceinline__ void pair_decode(int q, int& a, int& b) {
    int aa = 0, rem = q;
    while (rem >= 39 - aa) { rem -= 39 - aa; ++aa; }
    a = aa; b = aa + 1 + rem;
}

// ---------------- K1: layer0 (per-o block) + coef precompute + zeroing ----------------
__global__ __launch_bounds__(256) void k_l0c(
    const float* __restrict__ S, const float* __restrict__ W0, const float* __restrict__ b0,
    const float* __restrict__ Wh,
    float* __restrict__ XT, float* __restrict__ st,
    float* __restrict__ cm0, float* __restrict__ cm1,
    float* __restrict__ stB, float* __restrict__ accb)
{
    const int tid = threadIdx.x;
    const int o = blockIdx.x;

    if (o == 0) { // zero stB accumulators (R/C/TR/T) + acc for this call (graph replay safe)
        for (int t = tid; t < 10624; t += 256) {
            if (t < 10496) stB[ST_R + t] = 0.f;
            else           accb[t - 10496] = 0.f;
        }
    }

    // ---- coefficient precompute (validated round-8: coalesced writes) ----
    {
        const int idx = o * 256 + tid;                // 0..32767
        const int l = idx >> 14;
        const int r2 = idx & 16383;
        const int oo = r2 & 127;                      // coalesced cm writes
        const int ii = (r2 >> 7) & 127;
        const float* w = Wh + ((l * WID + oo) * WID + ii) * 15;
        float* cm = l ? cm1 : cm0;
        const int base = ii * 128 + oo;
        const float w0=w[0],w1=w[1],w2=w[2],w3=w[3],w4=w[4],w5=w[5],w6=w[6],w7=w[7],
                    w8=w[8],w9=w[9],w10=w[10],w11=w[11],w12=w[12],w13=w[13],w14=w[14];
        cm[ 0*CM_SZ1+base] = w6 - w7 - w12 + w14;
        cm[ 1*CM_SZ1+base] = w8 - w10 - w11 + w14;
        cm[ 2*CM_SZ1+base] = w5 - w7 - w11 - w13 + 2.f*w14;
        cm[ 3*CM_SZ1+base] = w9 - w10 - w12 - w13 + 2.f*w14;
        cm[ 4*CM_SZ1+base] = w7 - w14;
        cm[ 5*CM_SZ1+base] = w10 - w14;
        cm[ 6*CM_SZ1+base] = w11 - w14;
        cm[ 7*CM_SZ1+base] = w12 - w14;
        cm[ 8*CM_SZ1+base] = w0 - w1 - w2 - w3 + 2.f*w4;
        cm[ 9*CM_SZ1+base] = w1 - w4;
        cm[10*CM_SZ1+base] = w2 - w4;
        cm[11*CM_SZ1+base] = w13 - w14;
        cm[12*CM_SZ1+base] = w14;
        cm[13*CM_SZ1+base] = w3 - w4;
        cm[14*CM_SZ1+base] = w4;
    }

    // ---- layer 0 (symmetric basis, 11 ops) — validated round-2 math ----
    __shared__ float sS[NPTS * 5];
    __shared__ float sX[NN];
    __shared__ float sP[NN];
    __shared__ float sR[NPTS], sC[NPTS], sD[NPTS], sTT[2];

    for (int t = tid; t < NPTS * 5; t += 256) sS[t] = S[t];
    __syncthreads();
    for (int p = tid; p < NN; p += 256) {
        int a = p / NPTS, b = p % NPTS;
        float acc = 0.f;
#pragma unroll
        for (int k = 0; k < 5; ++k) acc += sS[a * 5 + k] * sS[b * 5 + k];
        sX[p] = acc;
    }
    __syncthreads();
    if (tid < NPTS) {
        float r = 0.f, c = 0.f;
        for (int jj = 0; jj < NPTS; ++jj) { r += sX[tid * NPTS + jj]; c += sX[jj * NPTS + tid]; }
        sR[tid] = r; sC[tid] = c; sD[tid] = sX[tid * 41];
    }
    __syncthreads();
    if (tid == 0) {
        float tr = 0.f, T = 0.f;
        for (int a = 0; a < NPTS; ++a) { tr += sD[a]; T += sR[a]; }
        sTT[0] = tr; sTT[1] = T;
    }
    __syncthreads();

    float w[11];
#pragma unroll
    for (int k = 0; k < 11; ++k) w[k] = W0[o * 11 + k];
    const float tr = sTT[0], T = sTT[1];
    const float cfX = w[6] - w[7] - w[8] + w[10];
    const float cfd = w[5] - w[7] - w[8] - w[9] + 2.f * w[10];
    const float cfR = w[7] - w[10];
    const float cfC = w[8] - w[10];
    const float so  = w[9] * tr + w[10] * (T - tr) + b0[o * 2 + 1];
    const float cdd = w[0] - w[1] - w[2] - w[3] + 2.f * w[4];
    const float cdR = w[1] - w[4];
    const float cdC = w[2] - w[4];
    const float sd  = w[3] * tr + w[4] * (T - tr) + b0[o * 2 + 0];

    for (int p = tid; p < NN; p += 256) {
        int a = p / NPTS, b = p % NPTS;
        float v;
        if (a == b) {
            v = cdd * sD[a] + cdR * sR[a] + cdC * sC[a] + sd;
        } else {
            float xs = sX[p] + sX[b * NPTS + a];
            v = cfX * xs + cfd * (sD[a] + sD[b]) + cfR * (sR[a] + sR[b]) + cfC * (sC[a] + sC[b]) + so;
        }
        sP[p] = lrelu(v);
    }
    __syncthreads();
    for (int p = tid; p < NN; p += 256) XT[p * WID + o] = sP[p];
    if (tid < NPTS) {
        float r = 0.f, c = 0.f;
        for (int jj = 0; jj < NPTS; ++jj) { r += sP[tid * NPTS + jj]; c += sP[jj * NPTS + tid]; }
        st[ST_D + o * NPTS + tid] = sP[tid * 41];
        st[ST_R + o * NPTS + tid] = r;
        st[ST_C + o * NPTS + tid] = c;
        sR[tid] = r; sD[tid] = sP[tid * 41];
    }
    __syncthreads();
    if (tid == 0) {
        float t2 = 0.f, T2 = 0.f;
        for (int a = 0; a < NPTS; ++a) { t2 += sD[a]; T2 += sR[a]; }
        st[ST_TR + o] = t2; st[ST_T + o] = T2;
    }
}

// ---------------- K2: hidden layer 1, inline vt1 (validated round-4) + stats1 atomics ----------------
__global__ __launch_bounds__(256) void k_hid1(
    const float* __restrict__ XTA, const float* __restrict__ stA,
    const float* __restrict__ cm, const float* __restrict__ bl,
    float* __restrict__ XTB, float* __restrict__ stB)
{
    const int tid = threadIdx.x, blk = blockIdx.x;
    const int j = tid >> 7, o = tid & 127;
    const bool diag = (blk < 40);
    int e0, e1, e2, e3;
    pair_decode(2 * blk, e0, e1);
    pair_decode(2 * blk + 1, e2, e3);
    const int epl[5] = { e0, e1, e2, e3, diag ? blk : 0 };
    const int nep = diag ? 5 : 4;

    __shared__ float sD[5][128], sR[5][128], sC[5][128], sTr[128], sT[128];
    __shared__ float sxab[2][128], sxba[2][128];
    __shared__ float vpart[11][2][128];
    __shared__ float svt[11][128];

    for (int t = tid; t < nep * 128; t += 256) {
        const int e = t >> 7, k = t & 127, a = epl[e];
        sD[e][k] = stA[ST_D + k * 40 + a];
        sR[e][k] = stA[ST_R + k * 40 + a];
        sC[e][k] = stA[ST_C + k * 40 + a];
    }
    if (tid < 128) { sTr[o] = stA[ST_TR + o]; sT[o] = stA[ST_T + o]; }
    {
        const int a = epl[2 * j], b = epl[2 * j + 1];
        sxab[j][o] = XTA[(a * 40 + b) * 128 + o];
        sxba[j][o] = XTA[(b * 40 + a) * 128 + o];
    }
    __syncthreads();

    // inline vterm accumulation (validated round-4): j splits the k range
    float fva0 = 0, fva1 = 0, fva2 = 0, fva3 = 0;
    float fvb0 = 0, fvb1 = 0, fvb2 = 0, fvb3 = 0;
    float fso = 0, fdg = 0, fsd = 0;
    const int k0 = 64 * j;
    for (int k = k0; k < k0 + 64; ++k) {
        const int c = k * 128 + o;
        const float m2 = cm[2*CM_SZ1+c], m3 = cm[3*CM_SZ1+c], m4 = cm[4*CM_SZ1+c],
                    m5 = cm[5*CM_SZ1+c], m6 = cm[6*CM_SZ1+c], m7 = cm[7*CM_SZ1+c];
        {
            const float d = sD[0][k], r = sR[0][k], cc = sC[0][k];
            fva0 += m2*d + m4*r + m6*cc; fvb0 += m3*d + m5*r + m7*cc;
        }
        {
            const float d = sD[1][k], r = sR[1][k], cc = sC[1][k];
            fva1 += m2*d + m4*r + m6*cc; fvb1 += m3*d + m5*r + m7*cc;
        }
        {
            const float d = sD[2][k], r = sR[2][k], cc = sC[2][k];
            fva2 += m2*d + m4*r + m6*cc; fvb2 += m3*d + m5*r + m7*cc;
        }
        {
            const float d = sD[3][k], r = sR[3][k], cc = sC[3][k];
            fva3 += m2*d + m4*r + m6*cc; fvb3 += m3*d + m5*r + m7*cc;
        }
        fso += cm[11*CM_SZ1+c] * sTr[k] + cm[12*CM_SZ1+c] * sT[k];
        if (diag) {
            fdg += cm[8*CM_SZ1+c]*sD[4][k] + cm[9*CM_SZ1+c]*sR[4][k] + cm[10*CM_SZ1+c]*sC[4][k];
            fsd += cm[13*CM_SZ1+c]*sTr[k] + cm[14*CM_SZ1+c]*sT[k];
        }
    }
    vpart[0][j][o]=fva0; vpart[1][j][o]=fva1; vpart[2][j][o]=fva2; vpart[3][j][o]=fva3;
    vpart[4][j][o]=fvb0; vpart[5][j][o]=fvb1; vpart[6][j][o]=fvb2; vpart[7][j][o]=fvb3;
    vpart[8][j][o]=fso; vpart[9][j][o]=fdg; vpart[10][j][o]=fsd;
    __syncthreads();
    if (tid < 128) {
        for (int m = 0; m < 8; ++m) svt[m][o] = vpart[m][0][o] + vpart[m][1][o];
        svt[8][o]  = vpart[8][0][o] + vpart[8][1][o] + bl[o * 2 + 1];
        svt[9][o]  = vpart[9][0][o] + vpart[9][1][o];
        svt[10][o] = vpart[10][0][o] + vpart[10][1][o] + bl[o * 2 + 0];
    }
    __syncthreads();

    // main contraction (validated)
    float acc1 = 0.f, acc2 = 0.f;
#pragma unroll 8
    for (int i = 0; i < 128; ++i) {
        const float c1v = cm[i * 128 + o];
        const float c2v = cm[CM_SZ1 + i * 128 + o];
        const float xab = sxab[j][i], xba = sxba[j][i];
        acc1 += c1v * xab + c2v * xba;
        acc2 += c1v * xba + c2v * xab;
    }
    const int a = epl[2 * j], b = epl[2 * j + 1];
    const float so = svt[8][o];
    const float o1 = lrelu(acc1 + svt[2 * j][o]     + svt[4 + 2 * j + 1][o] + so);
    const float o2 = lrelu(acc2 + svt[2 * j + 1][o] + svt[4 + 2 * j][o]     + so);
    XTB[(a * 40 + b) * 128 + o] = o1;
    XTB[(b * 40 + a) * 128 + o] = o2;

    // stats1 accumulation: rows/cols (X1[a][b]=o1 contributes R[a],C[b]; X1[b][a]=o2 -> R[b],C[a])
    atomicAdd(&stB[ST_R + o * 40 + a], o1);
    atomicAdd(&stB[ST_C + o * 40 + b], o1);
    atomicAdd(&stB[ST_R + o * 40 + b], o2);
    atomicAdd(&stB[ST_C + o * 40 + a], o2);

    float xd = 0.f;
    if (diag && j == 0) {
        xd = lrelu(svt[9][o] + svt[10][o]);
        XTB[(blk * 41) * 128 + o] = xd;
        stB[ST_D + o * 40 + blk] = xd;                 // direct write (one writer)
        atomicAdd(&stB[ST_R + o * 40 + blk], xd);
        atomicAdd(&stB[ST_C + o * 40 + blk], xd);
        atomicAdd(&stB[ST_TR + o], xd);
    }
    // T total accumulation (one atomic per o per block) — validated round-4 pattern
    vpart[0][j][o] = o1 + o2 + xd;
    __syncthreads();
    if (tid < 128) atomicAdd(&stB[ST_T + o], vpart[0][0][o] + vpart[0][1][o]);
}

// ---------------- K3: hidden layer 2, inline vt2 from stB + pairs functionals ----------------
__global__ __launch_bounds__(256) void k_hid2(
    const float* __restrict__ XTB, const float* __restrict__ stB,
    const float* __restrict__ cm, const float* __restrict__ bl,
    const float* __restrict__ Wp, const float* __restrict__ Wi,
    float* __restrict__ praw, float* __restrict__ accb)
{
    const int tid = threadIdx.x, blk = blockIdx.x;
    const int j = tid >> 7, o = tid & 127;
    const bool diag = (blk < 40);
    int e0, e1, e2, e3;
    pair_decode(2 * blk, e0, e1);
    pair_decode(2 * blk + 1, e2, e3);
    const int epl[5] = { e0, e1, e2, e3, diag ? blk : 0 };
    const int nep = diag ? 5 : 4;

    __shared__ float sD[5][128], sR[5][128], sC[5][128], sTr[128], sT[128];
    __shared__ float sxab[2][128], sxba[2][128];
    __shared__ float vpart[11][2][128];
    __shared__ float svt[11][128];
    __shared__ float sxd[128];
    __shared__ float rr[7][2][128];

    // ---- stats loads from stB (cheap; replaces round-8's expensive recompute) ----
    for (int t = tid; t < nep * 128; t += 256) {
        const int e = t >> 7, k = t & 127, a = epl[e];
        sD[e][k] = stB[ST_D + k * 40 + a];
        sR[e][k] = stB[ST_R + k * 40 + a];
        sC[e][k] = stB[ST_C + k * 40 + a];
    }
    if (tid < 128) { sTr[o] = stB[ST_TR + o]; sT[o] = stB[ST_T + o]; }
    {
        const int a = epl[2 * j], b = epl[2 * j + 1];
        sxab[j][o] = XTB[(a * 40 + b) * 128 + o];
        sxba[j][o] = XTB[(b * 40 + a) * 128 + o];
    }
    __syncthreads();

    // ---- inline vterm accumulation (cm1) — validated round-4/8 body ----
    float fva0 = 0, fva1 = 0, fva2 = 0, fva3 = 0;
    float fvb0 = 0, fvb1 = 0, fvb2 = 0, fvb3 = 0;
    float fso = 0, fdg = 0, fsd = 0;
    const int k0 = 64 * j;
    for (int k = k0; k < k0 + 64; ++k) {
        const int c = k * 128 + o;
        const float m2 = cm[2*CM_SZ1+c], m3 = cm[3*CM_SZ1+c], m4 = cm[4*CM_SZ1+c],
                    m5 = cm[5*CM_SZ1+c], m6 = cm[6*CM_SZ1+c], m7 = cm[7*CM_SZ1+c];
        {
            const float d = sD[0][k], r = sR[0][k], cc = sC[0][k];
            fva0 += m2*d + m4*r + m6*cc; fvb0 += m3*d + m5*r + m7*cc;
        }
        {
            const float d = sD[1][k], r = sR[1][k], cc = sC[1][k];
            fva1 += m2*d + m4*r + m6*cc; fvb1 += m3*d + m5*r + m7*cc;
        }
        {
            const float d = sD[2][k], r = sR[2][k], cc = sC[2][k];
            fva2 += m2*d + m4*r + m6*cc; fvb2 += m3*d + m5*r + m7*cc;
        }
        {
            const float d = sD[3][k], r = sR[3][k], cc = sC[3][k];
            fva3 += m2*d + m4*r + m6*cc; fvb3 += m3*d + m5*r + m7*cc;
        }
        fso += cm[11*CM_SZ1+c] * sTr[k] + cm[12*CM_SZ1+c] * sT[k];
        if (diag) {
            fdg += cm[8*CM_SZ1+c]*sD[4][k] + cm[9*CM_SZ1+c]*sR[4][k] + cm[10*CM_SZ1+c]*sC[4][k];
            fsd += cm[13*CM_SZ1+c]*sTr[k] + cm[14*CM_SZ1+c]*sT[k];
        }
    }
    vpart[0][j][o]=fva0; vpart[1][j][o]=fva1; vpart[2][j][o]=fva2; vpart[3][j][o]=fva3;
    vpart[4][j][o]=fvb0; vpart[5][j][o]=fvb1; vpart[6][j][o]=fvb2; vpart[7][j][o]=fvb3;
    vpart[8][j][o]=fso; vpart[9][j][o]=fdg; vpart[10][j][o]=fsd;
    __syncthreads();
    if (tid < 128) {
        for (int m = 0; m < 8; ++m) svt[m][o] = vpart[m][0][o] + vpart[m][1][o];
        svt[8][o]  = vpart[8][0][o] + vpart[8][1][o] + bl[o * 2 + 1];
        svt[9][o]  = vpart[9][0][o] + vpart[9][1][o];
        svt[10][o] = vpart[10][0][o] + vpart[10][1][o] + bl[o * 2 + 0];
    }
    __syncthreads();

    // ---- main contraction -> x1, x2 (never stored) — validated ----
    float acc1 = 0.f, acc2 = 0.f;
#pragma unroll 8
    for (int i = 0; i < 128; ++i) {
        const float c1v = cm[i * 128 + o];
        const float c2v = cm[CM_SZ1 + i * 128 + o];
        const float xab = sxab[j][i], xba = sxba[j][i];
        acc1 += c1v * xab + c2v * xba;
        acc2 += c1v * xba + c2v * xab;
    }
    const int pa = epl[2 * j], pb = epl[2 * j + 1];
    const float so = svt[8][o];
    const float x1 = lrelu(acc1 + svt[2 * j][o]     + svt[4 + 2 * j + 1][o] + so);
    const float x2 = lrelu(acc2 + svt[2 * j + 1][o] + svt[4 + 2 * j][o]     + so);
    if (diag && j == 0) sxd[o] = lrelu(svt[9][o] + svt[10][o]);

    // ---- pairs-layer linear functionals (validated round-4) ----
    const float p0 = Wp[o*11+0], p1 = Wp[o*11+1], p2 = Wp[o*11+2], p3 = Wp[o*11+3],
                p4 = Wp[o*11+4], p5 = Wp[o*11+5], p6 = Wp[o*11+6], p7 = Wp[o*11+7],
                p8 = Wp[o*11+8], p9 = Wp[o*11+9], p10 = Wp[o*11+10];
    const float wi0 = Wi[o*2+0], wi1 = Wi[o*2+1];
    const float s12 = x1 + x2;
    rr[0][j][o] = (p6 - p7 - p8 + p10) * s12;
    rr[1][j][o] = (p7 - p10) * s12;
    rr[2][j][o] = (p8 - p10) * s12;
    rr[3][j][o] = (p5 - p9) * s12;
    rr[4][j][o] = p10 * s12;
    rr[5][j][o] = p9 * s12;
    rr[6][j][o] = wi1 * s12;
    __syncthreads();
    for (int stp = 64; stp > 0; stp >>= 1) {
        if (o < stp) {
            for (int m = 0; m < 7; ++m) rr[m][j][o] += rr[m][j][o + stp];
        }
        __syncthreads();
    }
    if (o == 0) {
        const float v = rr[0][j][0];
        praw[pa * 40 + pb] = v;
        praw[pb * 40 + pa] = v;
        atomicAdd(&accb[PVA + pa], rr[1][j][0]); atomicAdd(&accb[PVA + pb], rr[1][j][0]);
        atomicAdd(&accb[PVB + pa], rr[2][j][0]); atomicAdd(&accb[PVB + pb], rr[2][j][0]);
        atomicAdd(&accb[PDG + pa], rr[3][j][0]); atomicAdd(&accb[PDG + pb], rr[3][j][0]);
        atomicAdd(&accb[A_SOFF], rr[4][j][0]);
        atomicAdd(&accb[A_SDG],  rr[5][j][0]);
        atomicAdd(&accb[A_ISC],  rr[6][j][0]);
    }
    if (diag) {
        __syncthreads();
        const float xdv = (j == 0) ? sxd[o] : 0.f;
        rr[0][j][o] = (p1 - p4) * xdv;
        rr[1][j][o] = (p2 - p4) * xdv;
        rr[2][j][o] = (p0 - p3) * xdv;
        rr[3][j][o] = p4 * xdv;
        rr[4][j][o] = p3 * xdv;
        rr[5][j][o] = wi0 * xdv;
        __syncthreads();
        for (int stp = 64; stp > 0; stp >>= 1) {
            if (o < stp) {
                for (int m = 0; m < 6; ++m) rr[m][j][o] += rr[m][j][o + stp];
            }
            __syncthreads();
        }
        if (tid == 0) {
            atomicAdd(&accb[PVA + blk], rr[0][0][0]);
            atomicAdd(&accb[PVB + blk], rr[1][0][0]);
            atomicAdd(&accb[PDG + blk], rr[2][0][0]);
            atomicAdd(&accb[A_SOFF], rr[3][0][0]);
            atomicAdd(&accb[A_SDG],  rr[4][0][0]);
            atomicAdd(&accb[A_ISC],  rr[5][0][0]);
        }
    }
}

// ---------------- K4: final (1 block) — fp32 Jacobi (validated round-9) ----------------
__global__ __launch_bounds__(256) void k_final(
    const float* __restrict__ S, const float* __restrict__ praw,
    const float* __restrict__ acc, const float* __restrict__ bp,
    const float* __restrict__ bi, float* __restrict__ out)
{
    __shared__ float sm[2201];
    __shared__ float sU[5];
    const int tid = threadIdx.x;

    float* sPr = sm;          // 1600
    float* sSS = sm + 1600;   // 200
    float* M1  = sm + 1800;   // 200
    float* sA  = sm + 2000;   // 25

    for (int t = tid; t < NPTS * 5; t += 256) sSS[t] = S[t];
    const float psoff = acc[A_SOFF] + bp[1];
    const float psdg  = acc[A_SDG]  + bp[0];
    for (int p = tid; p < NN; p += 256) {
        const int a = p / NPTS, b = p % NPTS;
        float v;
        if (a == b) v = acc[PDG + a] + psdg;
        else        v = praw[p] + acc[PVA + a] + acc[PVB + b] + psoff;
        sPr[p] = v;
    }
    __syncthreads();
    if (tid < 200) {
        const int c = tid / NPTS, b = tid % NPTS;
        float s = 0.f;
        for (int a = 0; a < NPTS; ++a) s += sSS[a * 5 + c] * sPr[a * NPTS + b];
        M1[c * NPTS + b] = s;
    }
    __syncthreads();
    if (tid < 25) {
        const int c = tid / 5, d = tid % 5;
        float s = 0.f;
        for (int b = 0; b < NPTS; ++b) s += M1[c * NPTS + b] * sSS[b * 5 + d];
        sA[tid] = s;
    }
    __syncthreads();

    if (tid == 0) {
        const float isc = acc[A_ISC] + bi[0];
        float A[5][5], V[5][5];
#pragma unroll
        for (int c = 0; c < 5; ++c)
#pragma unroll
            for (int d = 0; d < 5; ++d)
                A[c][d] = (c >= d) ? sA[c * 5 + d] : sA[d * 5 + c];
#pragma unroll
        for (int c = 0; c < 5; ++c) A[c][c] += isc;
#pragma unroll
        for (int c = 0; c < 5; ++c)
#pragma unroll
            for (int d = 0; d < 5; ++d) V[c][d] = (c == d) ? 1.f : 0.f;

        float dscale = 1.f;
#pragma unroll
        for (int c = 0; c < 5; ++c) dscale += A[c][c] * A[c][c];
        for (int sweep = 0; sweep < 15; ++sweep) {
            float off = 0.f;
#pragma unroll
            for (int p = 0; p < 4; ++p)
#pragma unroll
                for (int q = p + 1; q < 5; ++q) off += A[p][q] * A[p][q];
            if (off < 1e-11f * dscale) break;
#pragma unroll
            for (int p = 0; p < 4; ++p) {
#pragma unroll
                for (int q = p + 1; q < 5; ++q) {
                    const float apq = A[p][q];
                    if (fabsf(apq) < 1e-30f) continue;
                    const float theta = (A[q][q] - A[p][p]) / (2.f * apq);
                    const float t = (theta >= 0.f ? 1.f : -1.f) / (fabsf(theta) + sqrtf(theta * theta + 1.f));
                    const float cth = 1.f / sqrtf(t * t + 1.f);
                    const float sth = t * cth;
#pragma unroll
                    for (int k = 0; k < 5; ++k) {
                        const float akp = A[k][p], akq = A[k][q];
                        A[k][p] = cth * akp - sth * akq;
                        A[k][q] = sth * akp + cth * akq;
                    }
#pragma unroll
                    for (int k = 0; k < 5; ++k) {
                        const float apk = A[p][k], aqk = A[q][k];
                        A[p][k] = cth * apk - sth * aqk;
                        A[q][k] = sth * apk + cth * aqk;
                    }
#pragma unroll
                    for (int k = 0; k < 5; ++k) {
                        const float vkp = V[k][p], vkq = V[k][q];
                        V[k][p] = cth * vkp - sth * vkq;
                        V[k][q] = sth * vkp + cth * vkq;
                    }
                }
            }
        }
        int best = 0;
#pragma unroll
        for (int k = 1; k < 5; ++k) if (A[k][k] > A[best][best]) best = k;
        float u[5];
#pragma unroll
        for (int k = 0; k < 5; ++k) u[k] = V[k][best];
        int jm = 0; float am = fabsf(u[0]);
#pragma unroll
        for (int k = 1; k < 5; ++k) if (fabsf(u[k]) > am) { am = fabsf(u[k]); jm = k; }
        if (u[jm] < 0.f) {
#pragma unroll
            for (int k = 0; k < 5; ++k) u[k] = -u[k];
        }
#pragma unroll
        for (int k = 0; k < 5; ++k) sU[k] = u[k];
    }
    __syncthreads();
    if (tid < NPTS) {
        float s = 0.f;
#pragma unroll
        for (int k = 0; k < 5; ++k) s += sSS[tid * 5 + k] * sU[k];
        out[tid] = s;
    }
}

extern "C" void kernel_launch(void* const* d_in, const int* in_sizes, int n_in,
                              void* d_out, int out_size, void* d_ws, size_t ws_size,
                              hipStream_t stream) {
    const float* S  = (const float*)d_in[0];
    // d_in[1..3] basis tensors: unused (structure derived analytically)
    const float* W0 = (const float*)d_in[4];
    const float* b0 = (const float*)d_in[5];
    const float* Wh = (const float*)d_in[6];
    const float* bh = (const float*)d_in[7];
    const float* Wp = (const float*)d_in[8];
    const float* bp = (const float*)d_in[9];
    const float* Wi = (const float*)d_in[10];
    const float* bi = (const float*)d_in[11];
    float* outf = (float*)d_out;
    float* ws = (float*)d_ws;
    if (ws_size < (size_t)WS_TOTAL * sizeof(float)) return;

    float* XTA  = ws + WS_XTA;
    float* XTB  = ws + WS_XTB;
    float* stA  = ws + WS_STA;
    float* stB  = ws + WS_STB;
    float* cm0  = ws + WS_CM0;
    float* cm1  = ws + WS_CM1;
    float* praw = ws + WS_PRAW;
    float* acc  = ws + WS_ACC;

    k_l0c<<<WID, 256, 0, stream>>>(S, W0, b0, Wh, XTA, stA, cm0, cm1, stB, acc);
    k_hid1<<<390, 256, 0, stream>>>(XTA, stA, cm0, bh, XTB, stB);
    k_hid2<<<390, 256, 0, stream>>>(XTB, stB, cm1, bh + 2 * WID, Wp, Wi, praw, acc);
    k_final<<<1, 256, 0, stream>>>(S, praw, acc, bp, bi, outf);
}